// Round 14
// baseline (111.481 us; speedup 1.0000x reference)
//
#include <hip/hip_runtime.h>
#include <hip/hip_bf16.h>
#include <stdint.h>

// ---------------------------------------------------------------------------
// SNN: x[512,784] -> FC(784->1024)+LIF -> FC(1024->1024)+LIF -> FC(1024->10)+LIF
// T=32, tau=2, vth=1, hard reset. Out = spike counts [512,10].
//
// Verified (R5-R13, absmax=0): layer-0 LIF exactly periodic (class=ctz+1);
// layer-1 current = divisor sum over class weight-sums; cur0 = exact 3-way
// bf16-split (6 cross-terms hh,hm,mh,mm,hl,lh) MFMA GEMM, split-K x10.
//
// R14 changes (one theory: gemm under-occupied, prep over-writing):
//  - 64x64 gemm tiles -> grid (8,16,10) = 1280 blocks (~5/CU vs 1.25) for
//    latency hiding. Per-element K-chains identical -> Cpart bit-identical.
//  - Ax/Bw stored as 3 components (h,m,l; 2400-wide), 6-segment schedule via
//    wave-uniform offset tables (s = kk/800; 800%32==0 so iters segment-pure).
//    Prep write traffic 14 -> 7 MB.
// Structure: prep_k -> gemm0t_k (gemm + W1 transpose) -> tail_k (R10 fused).
// ---------------------------------------------------------------------------

typedef __bf16 bf16x8 __attribute__((ext_vector_type(8)));
typedef float  f32x4  __attribute__((ext_vector_type(4)));

__device__ __forceinline__ void gload16(const void* g, void* l) {
  __builtin_amdgcn_global_load_lds((const __attribute__((address_space(1))) void*)g,
                                   (__attribute__((address_space(3))) void*)l,
                                   16, 0, 0);
}

__device__ __forceinline__ void bsplit3(float v, __hip_bfloat16& h,
                                        __hip_bfloat16& m, __hip_bfloat16& l) {
  h = __float2bfloat16(v);
  float r1 = v - __bfloat162float(h);
  m = __float2bfloat16(r1);
  float r2 = r1 - __bfloat162float(m);
  l = __float2bfloat16(r2);
}

// ---------------- prep: 3-component bf16 splits of x & W0 -------------------
// Ax[512][2400]: h @0, m @800, l @1600. Bw[1024][2400]: same layout.
// k in [784,800) zero-padded. [0,1600) splitx, [1600,4800) splitw.
__global__ __launch_bounds__(256) void prep_k(const float* __restrict__ x,
                                              const float* __restrict__ W0,
                                              __hip_bfloat16* __restrict__ Ax,
                                              __hip_bfloat16* __restrict__ Bw) {
  const int bid = blockIdx.x, tid = threadIdx.x;
  if (bid < 1600) {                       // splitx: 512*800 elements
    int i = bid * 256 + tid;
    int m = i / 800, k = i - m * 800;
    float v = (k < 784) ? x[(size_t)m * 784 + k] : 0.f;
    __hip_bfloat16 h, mm, l;
    bsplit3(v, h, mm, l);
    size_t base = (size_t)m * 2400;
    Ax[base + k] = h;
    Ax[base + 800 + k] = mm;
    Ax[base + 1600 + k] = l;
  } else {                                // splitw: 1024*800 elements
    int i = (bid - 1600) * 256 + tid;
    int n = i / 800, k = i - n * 800;
    float v = (k < 784) ? W0[(size_t)n * 784 + k] : 0.f;
    __hip_bfloat16 h, mm, l;
    bsplit3(v, h, mm, l);
    size_t base = (size_t)n * 2400;
    Bw[base + k] = h;
    Bw[base + 800 + k] = mm;
    Bw[base + 1600 + k] = l;
  }
}

// ---------------- gemm0 split-K 64x64 (global_load_lds) + W1 transpose ------
// Blocks [0,1280): gemm, decode bx(8) x by(16) x bz(10), K-chunk = 480.
// Virtual K=4800 in 6 segments of 800; segment s uses component offA[s] of
// Ax and offB[s] of Bw ({hh,hm,mh,mm,hl,lh}). Blocks [1280,2304): W1
// transpose 32x32 tiles. Staging swizzle identical to R9 within each
// 16-row group -> LDS bit-layout and Cpart unchanged.
__global__ __launch_bounds__(256, 2) void gemm0t_k(const __hip_bfloat16* __restrict__ A,
                                                   const __hip_bfloat16* __restrict__ B,
                                                   const float* __restrict__ W1,
                                                   float* __restrict__ W1T,
                                                   float* __restrict__ Cpart) {
  __shared__ __align__(16) char smem[8192];
  const int bid = blockIdx.x, tid = threadIdx.x;

  if (bid >= 1280) {                      // ---- W1 transpose tiles ----
    float (*t)[33] = (float(*)[33])smem;  // 4.2 KB of the 8 KB
    int tt = bid - 1280;
    int c0 = (tt & 31) * 32, r0 = (tt >> 5) * 32;
    int lx = tid & 31, ly = tid >> 5;     // 32 x 8
#pragma unroll
    for (int i = 0; i < 32; i += 8)
      t[ly + i][lx] = W1[(size_t)(r0 + ly + i) * 1024 + (c0 + lx)];
    __syncthreads();
#pragma unroll
    for (int i = 0; i < 32; i += 8)
      W1T[(size_t)(c0 + ly + i) * 1024 + (r0 + lx)] = t[lx][ly + i];
    return;
  }

  // ---- gemm blocks: 64x64 tile, 4 waves, each wave -> 32x32 quadrant ----
  __hip_bfloat16* As = (__hip_bfloat16*)smem;          // [64][32]
  __hip_bfloat16* Bs = As + 64 * 32;                   // [64][32]
  const int bx = bid & 7, by = (bid >> 3) & 15, bz = bid >> 7;
  const int wave = tid >> 6, lane = tid & 63, quad = lane >> 4, l16 = lane & 15;
  const int wm = (wave >> 1) * 32, wn = (wave & 1) * 32;
  const int mbase = bx * 64, nbase = by * 64, kbase = bz * 480;
  const int srow = lane >> 2;
  const int gq = (lane & 3) ^ ((lane >> 3) & 3);
  const int swz = (l16 >> 1) & 3;
  const int offA[6] = {0, 0, 800, 800, 0, 1600};       // A comp: h,h,m,m,h,l
  const int offB[6] = {0, 800, 0, 800, 1600, 0};       // B comp: h,m,h,m,l,h

  f32x4 acc[2][2] = {};

  for (int kk = kbase; kk < kbase + 480; kk += 32) {
    const int s = kk / 800;                            // wave-uniform, 0..5
    const int kloc = kk - s * 800;
    const int kA = kloc + offA[s], kB = kloc + offB[s];
    // wave w stages rows 16w..16w+15 of A and of B (1 gload16 each)
    gload16(A + (size_t)(mbase + wave * 16 + srow) * 2400 + kA + gq * 8,
            (char*)As + wave * 1024);
    gload16(B + (size_t)(nbase + wave * 16 + srow) * 2400 + kB + gq * 8,
            (char*)Bs + wave * 1024);
    __syncthreads();
    bf16x8 af[2], bfr[2];
#pragma unroll
    for (int i = 0; i < 2; ++i)
      af[i] = *(const bf16x8*)((const __bf16*)As + (wm + i * 16 + l16) * 32 + ((quad ^ swz) * 8));
#pragma unroll
    for (int j = 0; j < 2; ++j)
      bfr[j] = *(const bf16x8*)((const __bf16*)Bs + (wn + j * 16 + l16) * 32 + ((quad ^ swz) * 8));
#pragma unroll
    for (int i = 0; i < 2; ++i)
#pragma unroll
      for (int j = 0; j < 2; ++j)
        acc[i][j] = __builtin_amdgcn_mfma_f32_16x16x32_bf16(af[i], bfr[j], acc[i][j], 0, 0, 0);
    __syncthreads();
  }

  float* Cz = Cpart + (size_t)bz * 512 * 1024;
#pragma unroll
  for (int i = 0; i < 2; ++i)
#pragma unroll
    for (int j = 0; j < 2; ++j)
#pragma unroll
      for (int r = 0; r < 4; ++r) {
        int m = mbase + wm + i * 16 + quad * 4 + r;
        int n = nbase + wn + j * 16 + l16;
        Cz[(size_t)m * 1024 + n] = acc[i][j][r];
      }
}

// ---------------- fused tail (compact0 + layer1 + layer2), R10 verbatim -----
struct TailSM {
  unsigned short sidx[1024];
  int sseg[33];
  int mtot;
  unsigned l2i[1024];
  unsigned l2w[1024];
  union {
    struct { int whist[16][33]; int clstot[33]; int clsofs[34]; int wofs[16][33]; } s3;
    struct { int wtot[16]; int wbase[16]; } s4;
    struct { float sW2[10 * 1025]; float scur[320]; } s5;
  } u;
};

__global__ __launch_bounds__(1024) void tail_k(const float* __restrict__ Cpart,
                                               const float* __restrict__ b0,
                                               const float* __restrict__ W1T,
                                               const float* __restrict__ b1,
                                               const float* __restrict__ W2,
                                               const float* __restrict__ b2,
                                               float* __restrict__ out) {
  __shared__ TailSM sm;
  const int b = blockIdx.x, o = threadIdx.x;
  const int wave = o >> 6, lane = o & 63;

  // ---- S3: split-K reduce + LIF + class compaction ----
  {
    float cur = 0.f;
#pragma unroll
    for (int z = 0; z < 10; ++z)
      cur += Cpart[(size_t)z * 512 * 1024 + (size_t)b * 1024 + o];
    cur += b0[o];
    float v = 0.f;
    unsigned word = 0u;
#pragma unroll
    for (int t = 0; t < 32; ++t) {
      v = v + (cur - v) * 0.5f;            // exact: /2.0 == *0.5f
      if (v >= 1.0f) { word |= 1u << t; v = 0.f; }
    }
    int n = word ? (__builtin_ctz(word) + 1) : 0;
    unsigned long long mymask = 0ull;
#pragma unroll 1
    for (int c = 1; c <= 32; ++c) {
      unsigned long long m = __ballot(n == c);
      if (lane == 0) sm.u.s3.whist[wave][c] = __popcll(m);
      if (n == c) mymask = m;
    }
    __syncthreads();
    if (o < 32) {
      int c = o + 1, s = 0;
#pragma unroll
      for (int w = 0; w < 16; ++w) s += sm.u.s3.whist[w][c];
      sm.u.s3.clstot[c] = s;
    }
    __syncthreads();
    if (o == 0) {
      int run = 0;
#pragma unroll
      for (int c = 1; c <= 32; ++c) { sm.u.s3.clsofs[c] = run; run += sm.u.s3.clstot[c]; }
      sm.u.s3.clsofs[33] = run;
    }
    __syncthreads();
    if (o < 32) {
      int c = o + 1, s = sm.u.s3.clsofs[c];
#pragma unroll
      for (int w = 0; w < 16; ++w) { sm.u.s3.wofs[w][c] = s; s += sm.u.s3.whist[w][c]; }
    }
    __syncthreads();
    if (n) {
      int pos = sm.u.s3.wofs[wave][n] + __popcll(mymask & ((1ull << lane) - 1ull));
      sm.sidx[pos] = (unsigned short)o;
    }
    if (o < 33) sm.sseg[o] = sm.u.s3.clsofs[o + 1];
  }
  __syncthreads();

  // ---- S4: layer-1 class-sums + divisor LIF + compaction ----
  {
    float S[32];
#pragma unroll
    for (int c = 0; c < 32; ++c) {
      int j0 = __builtin_amdgcn_readfirstlane((c == 0) ? 0 : sm.sseg[c - 1]);
      int j1 = __builtin_amdgcn_readfirstlane(sm.sseg[c]);
      float s = 0.f;
      for (int j = j0; j < j1; ++j)
        s += W1T[(size_t)sm.sidx[j] * 1024 + o];
      S[c] = s;
    }
    const float bias = b1[o];
    float v = 0.f;
    unsigned word = 0u;
#pragma unroll
    for (int t = 0; t < 32; ++t) {
      float cur = 0.f;
#pragma unroll
      for (int c = 1; c <= 32; ++c)
        if ((t + 1) % c == 0) cur += S[c - 1];   // compile-time divisor table
      float xc = cur + bias;
      v = v + (xc - v) * 0.5f;
      if (v >= 1.0f) { word |= 1u << t; v = 0.f; }
    }
    bool act = (word != 0u);
    unsigned long long m = __ballot(act);
    if (lane == 0) sm.u.s4.wtot[wave] = __popcll(m);
    __syncthreads();
    if (o == 0) {
      int s = 0;
#pragma unroll
      for (int i = 0; i < 16; ++i) { sm.u.s4.wbase[i] = s; s += sm.u.s4.wtot[i]; }
      sm.mtot = s;
    }
    __syncthreads();
    if (act) {
      int pos = sm.u.s4.wbase[wave] + __popcll(m & ((1ull << lane) - 1ull));
      sm.l2i[pos] = (unsigned)o;
      sm.l2w[pos] = word;
    }
  }
  __syncthreads();

  // ---- S5: layer-2 sparse FC + LIF + count ----
  {
    for (int i = o; i < 10240; i += 1024)
      sm.u.s5.sW2[(i >> 10) * 1025 + (i & 1023)] = W2[i];
    __syncthreads();
    const int mtot = sm.mtot;
    if (o < 320) {
      int t = o / 10, c = o - t * 10;
      float acc = 0.f;
      for (int j = 0; j < mtot; ++j) {
        unsigned wd = sm.l2w[j];
        float wv = sm.u.s5.sW2[c * 1025 + sm.l2i[j]];
        acc += ((wd >> t) & 1u) ? wv : 0.f;
      }
      sm.u.s5.scur[o] = acc;
    }
    __syncthreads();
    if (o < 10) {
      float v = 0.f, cnt2 = 0.f, bias = b2[o];
#pragma unroll
      for (int tt = 0; tt < 32; ++tt) {
        float xc = sm.u.s5.scur[tt * 10 + o] + bias;
        v = v + (xc - v) * 0.5f;
        if (v >= 1.0f) { cnt2 += 1.f; v = 0.f; }
      }
      out[(size_t)b * 10 + o] = cnt2;
    }
  }
}

// ---------------------------------------------------------------------------
extern "C" void kernel_launch(void* const* d_in, const int* in_sizes, int n_in,
                              void* d_out, int out_size, void* d_ws, size_t ws_size,
                              hipStream_t stream) {
  const float* x  = (const float*)d_in[0];   // [512,784]
  const float* W0 = (const float*)d_in[1];   // [1024,784]
  const float* b0 = (const float*)d_in[2];   // [1024]
  const float* W1 = (const float*)d_in[3];   // [1024,1024]
  const float* b1 = (const float*)d_in[4];   // [1024]
  const float* W2 = (const float*)d_in[5];   // [10,1024]
  const float* b2 = (const float*)d_in[6];   // [10]
  float* out = (float*)d_out;                // [512,10]

  char* ws = (char*)d_ws;
  size_t off = 0;
  auto alloc = [&](size_t bytes) -> char* {
    char* p = ws + off;
    off += (bytes + 255) & ~(size_t)255;
    return p;
  };
  __hip_bfloat16* Ax    = (__hip_bfloat16*)alloc((size_t)512 * 2400 * 2);   // 2.4 MB
  __hip_bfloat16* Bw    = (__hip_bfloat16*)alloc((size_t)1024 * 2400 * 2);  // 4.7 MB
  float*          Cpart = (float*)alloc((size_t)10 * 512 * 1024 * 4);       // 21 MB
  float*          W1T   = (float*)alloc((size_t)1024 * 1024 * 4);           // 4.2 MB
  (void)ws_size;

  prep_k<<<4800, 256, 0, stream>>>(x, W0, Ax, Bw);
  gemm0t_k<<<2304, 256, 0, stream>>>(Ax, Bw, W1, W1T, Cpart);
  tail_k<<<512, 1024, 0, stream>>>(Cpart, b0, W1T, b1, W2, b2, out);
}